// Round 6
// baseline (243.909 us; speedup 1.0000x reference)
//
#include <hip/hip_runtime.h>

// Problem constants: S=128, D=512, H=8, W=64, NUM=16, SCALE=sqrt(8)
// All inputs and outputs fp32 (reference dtypes); fp32 compute throughout.
// Frozen empirical facts (r0-r4): XT[k][129] transpose staging is the only
// fast GEMM staging (two "improvements" cost ~4x in proj4); fused packaging
// (proj2 + scores in ONE dispatch) is worth ~25 us of overlap; scores
// occupancy is NOT the bottleneck (r4: +50% residency -> +0).
// This round's single variable: ALL final-output stores are nontemporal
// (L2-bypass hint). The 154 MB/iter output stream was evicting the ~4 MB of
// hot projection data that 2304 blocks keep re-reading; output is never
// re-read, so caching it is pure pollution.
// (r5 compile fix: __builtin_nontemporal_store needs a NATIVE vector type,
// not HIP_vector_type<float,4> — use ext_vector_type(4).)
#define INV_SCALE 0.35355339059327373f
#define LOG2E 1.4426950408889634f

typedef float nat_f4 __attribute__((ext_vector_type(4)));

struct Proj4Args {
  const float* x[4];
  const float* w[4];
  const float* b[4];
  float* y[4];
};

// ---------------------------------------------------------------------------
// Linear GEMM body: y[s][dbase+h*4+di] = sum_k x[s][k]*W[dbase+h*4+di][k]+b.
// Thread t: s = t&127, h = t>>7. K walked in 512/CHUNK chunks.
// W tile (8 rows, 16KB) staged once in LDS; inner W reads are wave-uniform
// broadcast b128. X chunk transpose-staged k-major XT[k][129] (layout FROZEN
// per r1/r2 regressions) with register prefetch of chunk c+1.
// CHUNK=32 instantiation is bit-identical to the round-0 proven kernel.
// ---------------------------------------------------------------------------
template <int CHUNK>
__device__ __forceinline__ void gemm8_body(const float* xg, const float* wg_p,
                                           const float* bp, int dbase, int t,
                                           float* SH, float o[4]) {
  const int s = t & 127;
  const int h = t >> 7;
  float* WL = SH;                                // [8][512] = 4096 floats
  float(*XT)[129] = (float(*)[129])(SH + 4096);  // [CHUNK][129]
  {
    const float4* wg = (const float4*)(wg_p + dbase * 512);
    float4* wl4 = (float4*)WL;
#pragma unroll
    for (int r = 0; r < 4; ++r) wl4[t + r * 256] = wg[t + r * 256];
  }
  constexpr int C4 = CHUNK / 4;     // float4 cols per chunk row
  constexpr int RPT = C4 / 2;       // row-groups per thread
  constexpr int NCH = 512 / CHUNK;  // number of k chunks
  constexpr int RSTEP = 256 / C4;   // row stride between r-groups
  const int row = t / C4;
  const int col = t % C4;
  float acc[4] = {0.f, 0.f, 0.f, 0.f};
  float4 pre[RPT];
#pragma unroll
  for (int r = 0; r < RPT; ++r)
    pre[r] = ((const float4*)(xg + (row + r * RSTEP) * 512))[col];  // chunk 0
  for (int c = 0; c < NCH; ++c) {
    __syncthreads();  // also covers the W stage at c==0
#pragma unroll
    for (int r = 0; r < RPT; ++r) {
      float4 f = pre[r];
      int rr = row + r * RSTEP;
      XT[col * 4 + 0][rr] = f.x;
      XT[col * 4 + 1][rr] = f.y;
      XT[col * 4 + 2][rr] = f.z;
      XT[col * 4 + 3][rr] = f.w;
    }
    __syncthreads();
    if (c + 1 < NCH) {
#pragma unroll
      for (int r = 0; r < RPT; ++r)
        pre[r] =
            ((const float4*)(xg + (row + r * RSTEP) * 512))[(c + 1) * C4 + col];
    }
#pragma unroll
    for (int k4 = 0; k4 < C4; ++k4) {
      float xv0 = XT[k4 * 4 + 0][s];
      float xv1 = XT[k4 * 4 + 1][s];
      float xv2 = XT[k4 * 4 + 2][s];
      float xv3 = XT[k4 * 4 + 3][s];
#pragma unroll
      for (int di = 0; di < 4; ++di) {
        // wave-uniform address -> LDS broadcast read (free)
        const float4 wv =
            *(const float4*)&WL[(h * 4 + di) * 512 + c * CHUNK + k4 * 4];
        acc[di] = fmaf(wv.x, xv0, acc[di]);
        acc[di] = fmaf(wv.y, xv1, acc[di]);
        acc[di] = fmaf(wv.z, xv2, acc[di]);
        acc[di] = fmaf(wv.w, xv3, acc[di]);
      }
    }
  }
#pragma unroll
  for (int di = 0; di < 4; ++di) o[di] = acc[di] + bp[dbase + h * 4 + di];
}

__global__ __launch_bounds__(256) void proj4_kernel(Proj4Args A) {
  __shared__ float SH[8224];  // 4096 (WL) + 32*129 (XT) — round-0 identical
  const int blk = blockIdx.x;
  const int p = blk >> 6;
  const int dbase = (blk & 63) * 8;
  const int t = threadIdx.x;
  float o[4];
  gemm8_body<32>(A.x[p], A.w[p], A.b[p], dbase, t, SH, o);
  const int s = t & 127;
  const int h = t >> 7;
  // projections ARE re-read (by proj2 + scores): normal cached stores
  *(float4*)(A.y[p] + s * 512 + dbase + h * 4) = make_float4(o[0], o[1], o[2], o[3]);
}

// ---------------------------------------------------------------------------
// Fused second launch.
//   blocks 0..255      -> stage-2 projection + DIRECT final-output epilogue
//   blocks 256..2303   -> scores (softmax att), needs stage-1 only
// ---------------------------------------------------------------------------
struct FusedArgs {
  const float* w2[4];  // Wvo,Wqo,Wao,Wko
  const float* b2[4];
  const float* vp;
  const float* qp;
  const float* ap;
  const float* kp;
  float* out;
};

// Stage-2 direct epilogue (round-0 logic, gemm8_body<16>):
//   p=0: v_res[i,s,c]=vo[s,c*64+i]*A1v[s,i], A1v=INV_SCALE*sum_c vp*Sq*Sk
//   p=1: q_res (qo, A1q from qp,Sv,Sk);  p=2: a_res (ao, A1a from kp,Sv,Sq)
//   p=3: k_res[s, w*8+h] = ko[s, h*64+w]  (pure transpose)
// Final-output stores are nontemporal (never re-read).
__device__ __forceinline__ void proj2_direct_body(const FusedArgs& F, int blk,
                                                  int t, float* SH) {
  const int p = blk >> 6;
  const int dbase = (blk & 63) * 8;
  const float* xsrc[4] = {F.vp, F.qp, F.ap, F.kp};
  float o[4];
  gemm8_body<16>(xsrc[p], F.w2[p], F.b2[p], dbase, t, SH, o);
  const int s = t & 127;
  const int h = t >> 7;
  const int c_head = dbase >> 6;        // head index of this d-tile
  const int i0 = (dbase & 63) + h * 4;  // within-head coordinate base
  if (p == 3) {
    // k_res at flat offset 196608: [s, w*8 + head]
#pragma unroll
    for (int di = 0; di < 4; ++di)
      __builtin_nontemporal_store(
          o[di], &F.out[196608 + s * 512 + (i0 + di) * 8 + c_head]);
    return;  // p is block-uniform: no divergent-barrier hazard
  }
  const float* fac = (p == 0) ? F.vp : (p == 1) ? F.qp : F.kp;
  const float* S0 = (p == 0) ? F.qp : F.vp;
  const float* S1 = (p == 2) ? F.qp : F.kp;
  __syncthreads();  // all GEMM LDS reads done; reuse SH
  float* Sm = SH;   // [2][128][8] = 2048 floats
#pragma unroll
  for (int m = 0; m < 2; ++m) {
    const float* M = m ? S1 : S0;
#pragma unroll
    for (int cc = 0; cc < 4; ++cc) {
      const int c = h * 4 + cc;
      const float4* r4 = (const float4*)(M + s * 512 + c * 64);
      float sum = 0.f;
#pragma unroll
      for (int u = 0; u < 16; ++u) {
        float4 f = r4[u];
        sum += (f.x + f.y) + (f.z + f.w);
      }
      Sm[m * 1024 + s * 8 + c] = sum;
    }
  }
  __syncthreads();
  float prod[8];
#pragma unroll
  for (int c = 0; c < 8; ++c)
    prod[c] = Sm[s * 8 + c] * Sm[1024 + s * 8 + c];
#pragma unroll
  for (int di = 0; di < 4; ++di) {
    const int i = i0 + di;
    float A1 = 0.f;
#pragma unroll
    for (int c = 0; c < 8; ++c)
      A1 = fmaf(fac[s * 512 + c * 64 + i], prod[c], A1);
    // {v,q,a}_res at flat offset p*65536: [i, s*8 + head]
    __builtin_nontemporal_store(o[di] * (A1 * INV_SCALE),
                                &F.out[p * 65536 + i * 1024 + s * 8 + c_head]);
  }
}

// scores body: for each (s,i): att[j,l] = sum_c u[c]*tq[j,c]*ta[l,c];
// softmax over the 4096 contiguous (j,l); write fp32 at flat element
// 262144 + s*262144 + i*4096 + j*64 + l.
// blk = one s and 4 consecutive i. Thread t: j in {t>>3,(t>>3)+32},
// l in [(t&7)*8,+8) -> 16 values per i.
// No max-subtraction (logits sigma~1, max << 88: fp32 exp can't overflow);
// log2e folded into u[] so exp2f; float4 staging. Output stores nontemporal.
__device__ __forceinline__ void scores_body(const float* __restrict__ vp,
                                            const float* __restrict__ qp,
                                            const float* __restrict__ ap,
                                            float* __restrict__ out, int b,
                                            int t, float* SH) {
  const int s = b >> 4;
  const int i0 = (b & 15) * 4;
  float* tqL = SH;
  float* taL = SH + 512;
  float* uL = SH + 1024;                       // [ii][c]
  float(*redS)[4] = (float(*)[4])(SH + 1056);  // [ii][wid]
  if (t < 128)
    ((float4*)tqL)[t] = ((const float4*)(qp + s * 512))[t];
  else
    ((float4*)taL)[t - 128] = ((const float4*)(ap + s * 512))[t - 128];
  if (t < 32) {
    int ii = t >> 3, c = t & 7;
    uL[t] = vp[s * 512 + c * 64 + i0 + ii] * (INV_SCALE * LOG2E);
  }
  __syncthreads();
  const int j0 = t >> 3;       // 0..31
  const int l0 = (t & 7) * 8;  // 0..56
  float acc[4][16];
#pragma unroll
  for (int ii = 0; ii < 4; ++ii)
#pragma unroll
    for (int x = 0; x < 16; ++x) acc[ii][x] = 0.f;
#pragma unroll
  for (int c = 0; c < 8; ++c) {
    float t0 = tqL[c * 64 + j0];  // broadcast reads
    float t1 = tqL[c * 64 + j0 + 32];
    float4 A0 = *reinterpret_cast<const float4*>(&taL[c * 64 + l0]);
    float4 A1v = *reinterpret_cast<const float4*>(&taL[c * 64 + l0 + 4]);
    float ta8[8] = {A0.x, A0.y, A0.z, A0.w, A1v.x, A1v.y, A1v.z, A1v.w};
#pragma unroll
    for (int ii = 0; ii < 4; ++ii) {
      float uv = uL[ii * 8 + c];
      float m0 = uv * t0;
      float m1 = uv * t1;
#pragma unroll
      for (int x = 0; x < 8; ++x) {
        acc[ii][x] = fmaf(m0, ta8[x], acc[ii][x]);
        acc[ii][8 + x] = fmaf(m1, ta8[x], acc[ii][8 + x]);
      }
    }
  }
  const int wid = t >> 6, ln = t & 63;
#pragma unroll
  for (int ii = 0; ii < 4; ++ii) {
    float sl = 0.f;
#pragma unroll
    for (int x = 0; x < 16; ++x) {
      float e = exp2f(acc[ii][x]);  // acc carries log2e scaling
      acc[ii][x] = e;
      sl += e;
    }
#pragma unroll
    for (int o = 32; o; o >>= 1) sl += __shfl_xor(sl, o);
    if (ln == 0) redS[ii][wid] = sl;
  }
  __syncthreads();
  const long sbase = 262144L + (long)s * 262144 + (long)i0 * 4096;
#pragma unroll
  for (int ii = 0; ii < 4; ++ii) {
    float tot = (redS[ii][0] + redS[ii][1]) + (redS[ii][2] + redS[ii][3]);
    float sc = 1.0f / tot;
#pragma unroll
    for (int jj = 0; jj < 2; ++jj) {
      // wave-contiguous 16B stores (thread covers 32 contiguous bytes);
      // nontemporal: the 134 MB scores stream is never re-read
      nat_f4* pp = reinterpret_cast<nat_f4*>(
          out + sbase + ii * 4096 + (j0 + jj * 32) * 64 + l0);
      nat_f4 v0 = {acc[ii][jj * 8 + 0] * sc, acc[ii][jj * 8 + 1] * sc,
                   acc[ii][jj * 8 + 2] * sc, acc[ii][jj * 8 + 3] * sc};
      nat_f4 v1 = {acc[ii][jj * 8 + 4] * sc, acc[ii][jj * 8 + 5] * sc,
                   acc[ii][jj * 8 + 6] * sc, acc[ii][jj * 8 + 7] * sc};
      __builtin_nontemporal_store(v0, pp);
      __builtin_nontemporal_store(v1, pp + 1);
    }
  }
}

__global__ __launch_bounds__(256) void fused_kernel(FusedArgs F) {
  __shared__ float SH[6160];  // 4096 (WL) + 16*129 (XT) = 24.6 KB
  const int b = blockIdx.x;
  if (b < 256)
    proj2_direct_body(F, b, threadIdx.x, SH);
  else
    scores_body(F.vp, F.qp, F.ap, F.out, b - 256, threadIdx.x, SH);
}

extern "C" void kernel_launch(void* const* d_in, const int* in_sizes, int n_in,
                              void* d_out, int out_size, void* d_ws, size_t ws_size,
                              hipStream_t stream) {
  // setup_inputs order: v,q,a,k, 4 masks (unused), then Wv,bv,Wq,bq,Wa,ba,Wk,bk,
  //                     Wvo,bvo,Wqo,bqo,Wao,bao,Wko,bko
  int wb = 8;
  if (n_in >= 5 && in_sizes[4] == 262144) wb = 4;  // defensive: masks absent
  const float* W[8];
  const float* B[8];
  for (int i = 0; i < 8; ++i) {
    W[i] = (const float*)d_in[wb + 2 * i];
    B[i] = (const float*)d_in[wb + 2 * i + 1];
  }
  float* ws = (float*)d_ws;
  float* vp = ws;
  float* qp = ws + 65536;
  float* ap = ws + 131072;
  float* kp = ws + 196608;
  float* out = (float*)d_out;

  // Stage 1: input projections (vp = v@Wv^T+bv, etc.)
  Proj4Args a1;
  for (int i = 0; i < 4; ++i) {
    a1.x[i] = (const float*)d_in[i];
    a1.w[i] = W[i];
    a1.b[i] = B[i];
  }
  a1.y[0] = vp; a1.y[1] = qp; a1.y[2] = ap; a1.y[3] = kp;
  hipLaunchKernelGGL(proj4_kernel, dim3(256), dim3(256), 0, stream, a1);

  // Fused: stage-2 projections w/ direct final outputs (256) + scores (2048)
  FusedArgs F;
  for (int i = 0; i < 4; ++i) {
    F.w2[i] = W[4 + i];
    F.b2[i] = B[4 + i];
  }
  F.vp = vp; F.qp = qp; F.ap = ap; F.kp = kp; F.out = out;
  hipLaunchKernelGGL(fused_kernel, dim3(2304), dim3(256), 0, stream, F);
}

// Round 7
// 231.246 us; speedup vs baseline: 1.0548x; 1.0548x over previous
//
#include <hip/hip_runtime.h>

// Problem constants: S=128, D=512, H=8, W=64, NUM=16, SCALE=sqrt(8)
// All inputs and outputs fp32 (reference dtypes); fp32 compute throughout.
// Frozen empirical facts (r0-r6): XT[k][129] transpose staging is the only
// fast GEMM staging; fused packaging (proj2 + scores in ONE dispatch) is
// worth ~25 us; scores occupancy is NOT the bottleneck (r4); nontemporal
// stores REGRESS (r6: partial-line writes -> HBM RMW).
// This round's single variable: scores thread->(j,l) ownership remapped so
// every wave store instruction is FULLY CONTIGUOUS (64 lanes x 16B = 1KB,
// 16 full cache lines). Old mapping had lanes writing 16B at 32B stride
// (half-covered lines -> 2x L2 write transactions for the same 134 MB).
#define INV_SCALE 0.35355339059327373f
#define LOG2E 1.4426950408889634f

struct Proj4Args {
  const float* x[4];
  const float* w[4];
  const float* b[4];
  float* y[4];
};

// ---------------------------------------------------------------------------
// Linear GEMM body: y[s][dbase+h*4+di] = sum_k x[s][k]*W[dbase+h*4+di][k]+b.
// Thread t: s = t&127, h = t>>7. K walked in 512/CHUNK chunks.
// W tile (8 rows, 16KB) staged once in LDS; inner W reads are wave-uniform
// broadcast b128. X chunk transpose-staged k-major XT[k][129] (layout FROZEN
// per r1/r2 regressions) with register prefetch of chunk c+1.
// CHUNK=32 instantiation is bit-identical to the round-0 proven kernel.
// ---------------------------------------------------------------------------
template <int CHUNK>
__device__ __forceinline__ void gemm8_body(const float* xg, const float* wg_p,
                                           const float* bp, int dbase, int t,
                                           float* SH, float o[4]) {
  const int s = t & 127;
  const int h = t >> 7;
  float* WL = SH;                                // [8][512] = 4096 floats
  float(*XT)[129] = (float(*)[129])(SH + 4096);  // [CHUNK][129]
  {
    const float4* wg = (const float4*)(wg_p + dbase * 512);
    float4* wl4 = (float4*)WL;
#pragma unroll
    for (int r = 0; r < 4; ++r) wl4[t + r * 256] = wg[t + r * 256];
  }
  constexpr int C4 = CHUNK / 4;     // float4 cols per chunk row
  constexpr int RPT = C4 / 2;       // row-groups per thread
  constexpr int NCH = 512 / CHUNK;  // number of k chunks
  constexpr int RSTEP = 256 / C4;   // row stride between r-groups
  const int row = t / C4;
  const int col = t % C4;
  float acc[4] = {0.f, 0.f, 0.f, 0.f};
  float4 pre[RPT];
#pragma unroll
  for (int r = 0; r < RPT; ++r)
    pre[r] = ((const float4*)(xg + (row + r * RSTEP) * 512))[col];  // chunk 0
  for (int c = 0; c < NCH; ++c) {
    __syncthreads();  // also covers the W stage at c==0
#pragma unroll
    for (int r = 0; r < RPT; ++r) {
      float4 f = pre[r];
      int rr = row + r * RSTEP;
      XT[col * 4 + 0][rr] = f.x;
      XT[col * 4 + 1][rr] = f.y;
      XT[col * 4 + 2][rr] = f.z;
      XT[col * 4 + 3][rr] = f.w;
    }
    __syncthreads();
    if (c + 1 < NCH) {
#pragma unroll
      for (int r = 0; r < RPT; ++r)
        pre[r] =
            ((const float4*)(xg + (row + r * RSTEP) * 512))[(c + 1) * C4 + col];
    }
#pragma unroll
    for (int k4 = 0; k4 < C4; ++k4) {
      float xv0 = XT[k4 * 4 + 0][s];
      float xv1 = XT[k4 * 4 + 1][s];
      float xv2 = XT[k4 * 4 + 2][s];
      float xv3 = XT[k4 * 4 + 3][s];
#pragma unroll
      for (int di = 0; di < 4; ++di) {
        // wave-uniform address -> LDS broadcast read (free)
        const float4 wv =
            *(const float4*)&WL[(h * 4 + di) * 512 + c * CHUNK + k4 * 4];
        acc[di] = fmaf(wv.x, xv0, acc[di]);
        acc[di] = fmaf(wv.y, xv1, acc[di]);
        acc[di] = fmaf(wv.z, xv2, acc[di]);
        acc[di] = fmaf(wv.w, xv3, acc[di]);
      }
    }
  }
#pragma unroll
  for (int di = 0; di < 4; ++di) o[di] = acc[di] + bp[dbase + h * 4 + di];
}

__global__ __launch_bounds__(256) void proj4_kernel(Proj4Args A) {
  __shared__ float SH[8224];  // 4096 (WL) + 32*129 (XT) — round-0 identical
  const int blk = blockIdx.x;
  const int p = blk >> 6;
  const int dbase = (blk & 63) * 8;
  const int t = threadIdx.x;
  float o[4];
  gemm8_body<32>(A.x[p], A.w[p], A.b[p], dbase, t, SH, o);
  const int s = t & 127;
  const int h = t >> 7;
  *(float4*)(A.y[p] + s * 512 + dbase + h * 4) = make_float4(o[0], o[1], o[2], o[3]);
}

// ---------------------------------------------------------------------------
// Fused second launch.
//   blocks 0..255      -> stage-2 projection + DIRECT final-output epilogue
//   blocks 256..2303   -> scores (softmax att), needs stage-1 only
// ---------------------------------------------------------------------------
struct FusedArgs {
  const float* w2[4];  // Wvo,Wqo,Wao,Wko
  const float* b2[4];
  const float* vp;
  const float* qp;
  const float* ap;
  const float* kp;
  float* out;
};

// Stage-2 direct epilogue (round-0 logic, gemm8_body<16>):
//   p=0: v_res[i,s,c]=vo[s,c*64+i]*A1v[s,i], A1v=INV_SCALE*sum_c vp*Sq*Sk
//   p=1: q_res (qo, A1q from qp,Sv,Sk);  p=2: a_res (ao, A1a from kp,Sv,Sq)
//   p=3: k_res[s, w*8+h] = ko[s, h*64+w]  (pure transpose)
__device__ __forceinline__ void proj2_direct_body(const FusedArgs& F, int blk,
                                                  int t, float* SH) {
  const int p = blk >> 6;
  const int dbase = (blk & 63) * 8;
  const float* xsrc[4] = {F.vp, F.qp, F.ap, F.kp};
  float o[4];
  gemm8_body<16>(xsrc[p], F.w2[p], F.b2[p], dbase, t, SH, o);
  const int s = t & 127;
  const int h = t >> 7;
  const int c_head = dbase >> 6;        // head index of this d-tile
  const int i0 = (dbase & 63) + h * 4;  // within-head coordinate base
  if (p == 3) {
    // k_res at flat offset 196608: [s, w*8 + head]
#pragma unroll
    for (int di = 0; di < 4; ++di)
      F.out[196608 + s * 512 + (i0 + di) * 8 + c_head] = o[di];
    return;  // p is block-uniform: no divergent-barrier hazard
  }
  const float* fac = (p == 0) ? F.vp : (p == 1) ? F.qp : F.kp;
  const float* S0 = (p == 0) ? F.qp : F.vp;
  const float* S1 = (p == 2) ? F.qp : F.kp;
  __syncthreads();  // all GEMM LDS reads done; reuse SH
  float* Sm = SH;   // [2][128][8] = 2048 floats
#pragma unroll
  for (int m = 0; m < 2; ++m) {
    const float* M = m ? S1 : S0;
#pragma unroll
    for (int cc = 0; cc < 4; ++cc) {
      const int c = h * 4 + cc;
      const float4* r4 = (const float4*)(M + s * 512 + c * 64);
      float sum = 0.f;
#pragma unroll
      for (int u = 0; u < 16; ++u) {
        float4 f = r4[u];
        sum += (f.x + f.y) + (f.z + f.w);
      }
      Sm[m * 1024 + s * 8 + c] = sum;
    }
  }
  __syncthreads();
  float prod[8];
#pragma unroll
  for (int c = 0; c < 8; ++c)
    prod[c] = Sm[s * 8 + c] * Sm[1024 + s * 8 + c];
#pragma unroll
  for (int di = 0; di < 4; ++di) {
    const int i = i0 + di;
    float A1 = 0.f;
#pragma unroll
    for (int c = 0; c < 8; ++c)
      A1 = fmaf(fac[s * 512 + c * 64 + i], prod[c], A1);
    // {v,q,a}_res at flat offset p*65536: [i, s*8 + head]
    F.out[p * 65536 + i * 1024 + s * 8 + c_head] = o[di] * (A1 * INV_SCALE);
  }
}

// scores body: for each (s,i): att[j,l] = sum_c u[c]*tq[j,c]*ta[l,c];
// softmax over the 4096 contiguous (j,l); write fp32 at flat element
// 262144 + s*262144 + i*4096 + j*64 + l.
// NEW ownership (store-contiguous): thread (wid, ln) owns, per ii, the 16
// floats at flat positions (4*wid+k)*256 + 4*ln .. +4, k=0..3. Equivalent
// (j,l): j = 16*wid + 4*k + (ln>>4), l = 4*(ln&15)+e. Each of the 16 store
// instructions is a fully wave-contiguous 1KB (16 complete 64B lines) —
// the old mapping wrote 16B at 32B stride (32 half-covered lines/instr).
// LDS reads in the c-loop: tq = 4-way broadcast scalar, ta = b128 2-way
// (free per m136). No max-subtraction (logits sigma~1, max << 88, fp32 exp
// can't overflow); log2e folded into u[] so exp2f.
__device__ __forceinline__ void scores_body(const float* __restrict__ vp,
                                            const float* __restrict__ qp,
                                            const float* __restrict__ ap,
                                            float* __restrict__ out, int b,
                                            int t, float* SH) {
  const int s = b >> 4;
  const int i0 = (b & 15) * 4;
  float* tqL = SH;
  float* taL = SH + 512;
  float* uL = SH + 1024;                       // [ii][c]
  float(*redS)[4] = (float(*)[4])(SH + 1056);  // [ii][wid]
  if (t < 128)
    ((float4*)tqL)[t] = ((const float4*)(qp + s * 512))[t];
  else
    ((float4*)taL)[t - 128] = ((const float4*)(ap + s * 512))[t - 128];
  if (t < 32) {
    int ii = t >> 3, c = t & 7;
    uL[t] = vp[s * 512 + c * 64 + i0 + ii] * (INV_SCALE * LOG2E);
  }
  __syncthreads();
  const int wid = t >> 6, ln = t & 63;
  const int jb = 16 * wid + (ln >> 4);  // j for k=0 (then +4 per k)
  const int lq = (ln & 15) * 4;         // l base (4 consecutive l)
  float acc[4][16];                     // [ii][k*4+e]
#pragma unroll
  for (int ii = 0; ii < 4; ++ii)
#pragma unroll
    for (int x = 0; x < 16; ++x) acc[ii][x] = 0.f;
#pragma unroll
  for (int c = 0; c < 8; ++c) {
    const float* tq_c = &tqL[c * 64 + jb];
    float tj0 = tq_c[0];
    float tj1 = tq_c[4];
    float tj2 = tq_c[8];
    float tj3 = tq_c[12];
    float4 ta4 = *reinterpret_cast<const float4*>(&taL[c * 64 + lq]);
#pragma unroll
    for (int ii = 0; ii < 4; ++ii) {
      float uv = uL[ii * 8 + c];
      float m0 = uv * tj0;
      float m1 = uv * tj1;
      float m2 = uv * tj2;
      float m3 = uv * tj3;
      acc[ii][0] = fmaf(m0, ta4.x, acc[ii][0]);
      acc[ii][1] = fmaf(m0, ta4.y, acc[ii][1]);
      acc[ii][2] = fmaf(m0, ta4.z, acc[ii][2]);
      acc[ii][3] = fmaf(m0, ta4.w, acc[ii][3]);
      acc[ii][4] = fmaf(m1, ta4.x, acc[ii][4]);
      acc[ii][5] = fmaf(m1, ta4.y, acc[ii][5]);
      acc[ii][6] = fmaf(m1, ta4.z, acc[ii][6]);
      acc[ii][7] = fmaf(m1, ta4.w, acc[ii][7]);
      acc[ii][8] = fmaf(m2, ta4.x, acc[ii][8]);
      acc[ii][9] = fmaf(m2, ta4.y, acc[ii][9]);
      acc[ii][10] = fmaf(m2, ta4.z, acc[ii][10]);
      acc[ii][11] = fmaf(m2, ta4.w, acc[ii][11]);
      acc[ii][12] = fmaf(m3, ta4.x, acc[ii][12]);
      acc[ii][13] = fmaf(m3, ta4.y, acc[ii][13]);
      acc[ii][14] = fmaf(m3, ta4.z, acc[ii][14]);
      acc[ii][15] = fmaf(m3, ta4.w, acc[ii][15]);
    }
  }
#pragma unroll
  for (int ii = 0; ii < 4; ++ii) {
    float sl = 0.f;
#pragma unroll
    for (int x = 0; x < 16; ++x) {
      float e = exp2f(acc[ii][x]);  // acc carries log2e scaling
      acc[ii][x] = e;
      sl += e;
    }
#pragma unroll
    for (int o = 32; o; o >>= 1) sl += __shfl_xor(sl, o);
    if (ln == 0) redS[ii][wid] = sl;
  }
  __syncthreads();
  const long sbase = 262144L + (long)s * 262144 + (long)i0 * 4096;
#pragma unroll
  for (int ii = 0; ii < 4; ++ii) {
    float tot = (redS[ii][0] + redS[ii][1]) + (redS[ii][2] + redS[ii][3]);
    float sc = 1.0f / tot;
    // 4 stores, each wave-contiguous 1KB: float4 at base + k*256 + ln*4
    float* ob = out + sbase + ii * 4096 + wid * 1024 + ln * 4;
#pragma unroll
    for (int k = 0; k < 4; ++k) {
      *reinterpret_cast<float4*>(ob + k * 256) =
          make_float4(acc[ii][k * 4 + 0] * sc, acc[ii][k * 4 + 1] * sc,
                      acc[ii][k * 4 + 2] * sc, acc[ii][k * 4 + 3] * sc);
    }
  }
}

__global__ __launch_bounds__(256) void fused_kernel(FusedArgs F) {
  __shared__ float SH[6160];  // 4096 (WL) + 16*129 (XT) = 24.6 KB
  const int b = blockIdx.x;
  if (b < 256)
    proj2_direct_body(F, b, threadIdx.x, SH);
  else
    scores_body(F.vp, F.qp, F.ap, F.out, b - 256, threadIdx.x, SH);
}

extern "C" void kernel_launch(void* const* d_in, const int* in_sizes, int n_in,
                              void* d_out, int out_size, void* d_ws, size_t ws_size,
                              hipStream_t stream) {
  // setup_inputs order: v,q,a,k, 4 masks (unused), then Wv,bv,Wq,bq,Wa,ba,Wk,bk,
  //                     Wvo,bvo,Wqo,bqo,Wao,bao,Wko,bko
  int wb = 8;
  if (n_in >= 5 && in_sizes[4] == 262144) wb = 4;  // defensive: masks absent
  const float* W[8];
  const float* B[8];
  for (int i = 0; i < 8; ++i) {
    W[i] = (const float*)d_in[wb + 2 * i];
    B[i] = (const float*)d_in[wb + 2 * i + 1];
  }
  float* ws = (float*)d_ws;
  float* vp = ws;
  float* qp = ws + 65536;
  float* ap = ws + 131072;
  float* kp = ws + 196608;
  float* out = (float*)d_out;

  // Stage 1: input projections (vp = v@Wv^T+bv, etc.)
  Proj4Args a1;
  for (int i = 0; i < 4; ++i) {
    a1.x[i] = (const float*)d_in[i];
    a1.w[i] = W[i];
    a1.b[i] = B[i];
  }
  a1.y[0] = vp; a1.y[1] = qp; a1.y[2] = ap; a1.y[3] = kp;
  hipLaunchKernelGGL(proj4_kernel, dim3(256), dim3(256), 0, stream, a1);

  // Fused: stage-2 projections w/ direct final outputs (256) + scores (2048)
  FusedArgs F;
  for (int i = 0; i < 4; ++i) {
    F.w2[i] = W[4 + i];
    F.b2[i] = B[4 + i];
  }
  F.vp = vp; F.qp = qp; F.ap = ap; F.kp = kp; F.out = out;
  hipLaunchKernelGGL(fused_kernel, dim3(2304), dim3(256), 0, stream, F);
}

// Round 8
// 224.323 us; speedup vs baseline: 1.0873x; 1.0309x over previous
//
#include <hip/hip_runtime.h>

// Problem constants: S=128, D=512, H=8, W=64, NUM=16, SCALE=sqrt(8)
// All inputs and outputs fp32 (reference dtypes); fp32 compute throughout.
// Frozen empirical facts (r0-r7): XT[k][129] k-major transpose staging is the
// fast GEMM staging idiom; fused packaging (proj2 + scores in ONE dispatch)
// is worth ~25 us; scores occupancy is NOT the bottleneck (r4); nontemporal
// stores REGRESS (r6, partial-line RMW); wave-contiguous 1KB score stores
// are worth ~4-9 us (r7).
// This round's single variable: proj4 512 blocks (2/CU instead of 1/CU) —
// each block = (p, 8-d tile, 64-row s-half). At 1 block/CU every latency was
// fully exposed (10 us for 134 MFLOP). Fused kernel bit-identical to r7.
#define INV_SCALE 0.35355339059327373f
#define LOG2E 1.4426950408889634f

struct Proj4Args {
  const float* x[4];
  const float* w[4];
  const float* b[4];
  float* y[4];
};

// ---------------------------------------------------------------------------
// Stage-1 projection GEMM, 512 blocks: blk = (p<<7) | (dtile<<1) | shalf.
// Block computes y[p][shalf*64 .. +64][dbase .. dbase+8].
// Thread t: s = t&63 (local row), g = t>>6; computes di = g*2, g*2+1.
// W tile (8 rows, 16KB) staged once in LDS (wave-uniform broadcast reads).
// X half (64 rows) staged per 32-k chunk, k-major XT[k][65] (2-way bank
// aliasing only = free), register prefetch of chunk c+1.
// ---------------------------------------------------------------------------
__global__ __launch_bounds__(256) void proj4_kernel(Proj4Args A) {
  __shared__ float SH[6176];  // 4096 (WL 8x512) + 2080 (XT[32][65])
  const int blk = blockIdx.x;
  const int p = blk >> 7;
  const int dbase = ((blk >> 1) & 63) * 8;
  const int shalf = (blk & 1) * 64;
  const int t = threadIdx.x;
  const int s = t & 63;
  const int g = t >> 6;  // wave id; di pair = g*2 (wave-uniform)
  float* WL = SH;
  float(*XT)[65] = (float(*)[65])(SH + 4096);
  {
    const float4* wg = (const float4*)(A.w[p] + dbase * 512);
    float4* wl4 = (float4*)WL;
#pragma unroll
    for (int r = 0; r < 4; ++r) wl4[t + r * 256] = wg[t + r * 256];
  }
  const float* xg = A.x[p] + shalf * 512;  // this block's 64 rows
  const int row = t >> 3;  // 0..31; +32 covers rows 0..63
  const int col = t & 7;   // float4 column within the 32-k chunk
  float acc[2] = {0.f, 0.f};
  float4 pre[2];
#pragma unroll
  for (int r = 0; r < 2; ++r)
    pre[r] = ((const float4*)(xg + (row + r * 32) * 512))[col];  // chunk 0
  for (int c = 0; c < 16; ++c) {
    __syncthreads();  // also covers the W stage at c==0
#pragma unroll
    for (int r = 0; r < 2; ++r) {
      float4 f = pre[r];
      int rr = row + r * 32;
      XT[col * 4 + 0][rr] = f.x;
      XT[col * 4 + 1][rr] = f.y;
      XT[col * 4 + 2][rr] = f.z;
      XT[col * 4 + 3][rr] = f.w;
    }
    __syncthreads();
    if (c + 1 < 16) {
#pragma unroll
      for (int r = 0; r < 2; ++r)
        pre[r] = ((const float4*)(xg + (row + r * 32) * 512))[(c + 1) * 8 + col];
    }
#pragma unroll
    for (int k4 = 0; k4 < 8; ++k4) {
      float xv0 = XT[k4 * 4 + 0][s];
      float xv1 = XT[k4 * 4 + 1][s];
      float xv2 = XT[k4 * 4 + 2][s];
      float xv3 = XT[k4 * 4 + 3][s];
#pragma unroll
      for (int di = 0; di < 2; ++di) {
        // wave-uniform address -> LDS broadcast read (free)
        const float4 wv =
            *(const float4*)&WL[(g * 2 + di) * 512 + c * 32 + k4 * 4];
        acc[di] = fmaf(wv.x, xv0, acc[di]);
        acc[di] = fmaf(wv.y, xv1, acc[di]);
        acc[di] = fmaf(wv.z, xv2, acc[di]);
        acc[di] = fmaf(wv.w, xv3, acc[di]);
      }
    }
  }
  const float* bp = A.b[p] + dbase + g * 2;
  *(float2*)(A.y[p] + (shalf + s) * 512 + dbase + g * 2) =
      make_float2(acc[0] + bp[0], acc[1] + bp[1]);
}

// ---------------------------------------------------------------------------
// GEMM body for proj2 (r7 verbatim, CHUNK=16 instantiation).
// ---------------------------------------------------------------------------
template <int CHUNK>
__device__ __forceinline__ void gemm8_body(const float* xg, const float* wg_p,
                                           const float* bp, int dbase, int t,
                                           float* SH, float o[4]) {
  const int s = t & 127;
  const int h = t >> 7;
  float* WL = SH;                                // [8][512] = 4096 floats
  float(*XT)[129] = (float(*)[129])(SH + 4096);  // [CHUNK][129]
  {
    const float4* wg = (const float4*)(wg_p + dbase * 512);
    float4* wl4 = (float4*)WL;
#pragma unroll
    for (int r = 0; r < 4; ++r) wl4[t + r * 256] = wg[t + r * 256];
  }
  constexpr int C4 = CHUNK / 4;     // float4 cols per chunk row
  constexpr int RPT = C4 / 2;       // row-groups per thread
  constexpr int NCH = 512 / CHUNK;  // number of k chunks
  constexpr int RSTEP = 256 / C4;   // row stride between r-groups
  const int row = t / C4;
  const int col = t % C4;
  float acc[4] = {0.f, 0.f, 0.f, 0.f};
  float4 pre[RPT];
#pragma unroll
  for (int r = 0; r < RPT; ++r)
    pre[r] = ((const float4*)(xg + (row + r * RSTEP) * 512))[col];  // chunk 0
  for (int c = 0; c < NCH; ++c) {
    __syncthreads();  // also covers the W stage at c==0
#pragma unroll
    for (int r = 0; r < RPT; ++r) {
      float4 f = pre[r];
      int rr = row + r * RSTEP;
      XT[col * 4 + 0][rr] = f.x;
      XT[col * 4 + 1][rr] = f.y;
      XT[col * 4 + 2][rr] = f.z;
      XT[col * 4 + 3][rr] = f.w;
    }
    __syncthreads();
    if (c + 1 < NCH) {
#pragma unroll
      for (int r = 0; r < RPT; ++r)
        pre[r] =
            ((const float4*)(xg + (row + r * RSTEP) * 512))[(c + 1) * C4 + col];
    }
#pragma unroll
    for (int k4 = 0; k4 < C4; ++k4) {
      float xv0 = XT[k4 * 4 + 0][s];
      float xv1 = XT[k4 * 4 + 1][s];
      float xv2 = XT[k4 * 4 + 2][s];
      float xv3 = XT[k4 * 4 + 3][s];
#pragma unroll
      for (int di = 0; di < 4; ++di) {
        // wave-uniform address -> LDS broadcast read (free)
        const float4 wv =
            *(const float4*)&WL[(h * 4 + di) * 512 + c * CHUNK + k4 * 4];
        acc[di] = fmaf(wv.x, xv0, acc[di]);
        acc[di] = fmaf(wv.y, xv1, acc[di]);
        acc[di] = fmaf(wv.z, xv2, acc[di]);
        acc[di] = fmaf(wv.w, xv3, acc[di]);
      }
    }
  }
#pragma unroll
  for (int di = 0; di < 4; ++di) o[di] = acc[di] + bp[dbase + h * 4 + di];
}

// ---------------------------------------------------------------------------
// Fused second launch (r7 verbatim).
//   blocks 0..255      -> stage-2 projection + DIRECT final-output epilogue
//   blocks 256..2303   -> scores (softmax att), needs stage-1 only
// ---------------------------------------------------------------------------
struct FusedArgs {
  const float* w2[4];  // Wvo,Wqo,Wao,Wko
  const float* b2[4];
  const float* vp;
  const float* qp;
  const float* ap;
  const float* kp;
  float* out;
};

__device__ __forceinline__ void proj2_direct_body(const FusedArgs& F, int blk,
                                                  int t, float* SH) {
  const int p = blk >> 6;
  const int dbase = (blk & 63) * 8;
  const float* xsrc[4] = {F.vp, F.qp, F.ap, F.kp};
  float o[4];
  gemm8_body<16>(xsrc[p], F.w2[p], F.b2[p], dbase, t, SH, o);
  const int s = t & 127;
  const int h = t >> 7;
  const int c_head = dbase >> 6;        // head index of this d-tile
  const int i0 = (dbase & 63) + h * 4;  // within-head coordinate base
  if (p == 3) {
    // k_res at flat offset 196608: [s, w*8 + head]
#pragma unroll
    for (int di = 0; di < 4; ++di)
      F.out[196608 + s * 512 + (i0 + di) * 8 + c_head] = o[di];
    return;  // p is block-uniform: no divergent-barrier hazard
  }
  const float* fac = (p == 0) ? F.vp : (p == 1) ? F.qp : F.kp;
  const float* S0 = (p == 0) ? F.qp : F.vp;
  const float* S1 = (p == 2) ? F.qp : F.kp;
  __syncthreads();  // all GEMM LDS reads done; reuse SH
  float* Sm = SH;   // [2][128][8] = 2048 floats
#pragma unroll
  for (int m = 0; m < 2; ++m) {
    const float* M = m ? S1 : S0;
#pragma unroll
    for (int cc = 0; cc < 4; ++cc) {
      const int c = h * 4 + cc;
      const float4* r4 = (const float4*)(M + s * 512 + c * 64);
      float sum = 0.f;
#pragma unroll
      for (int u = 0; u < 16; ++u) {
        float4 f = r4[u];
        sum += (f.x + f.y) + (f.z + f.w);
      }
      Sm[m * 1024 + s * 8 + c] = sum;
    }
  }
  __syncthreads();
  float prod[8];
#pragma unroll
  for (int c = 0; c < 8; ++c)
    prod[c] = Sm[s * 8 + c] * Sm[1024 + s * 8 + c];
#pragma unroll
  for (int di = 0; di < 4; ++di) {
    const int i = i0 + di;
    float A1 = 0.f;
#pragma unroll
    for (int c = 0; c < 8; ++c)
      A1 = fmaf(fac[s * 512 + c * 64 + i], prod[c], A1);
    // {v,q,a}_res at flat offset p*65536: [i, s*8 + head]
    F.out[p * 65536 + i * 1024 + s * 8 + c_head] = o[di] * (A1 * INV_SCALE);
  }
}

// scores body (r7 verbatim): thread (wid, ln) owns, per ii, the 16 floats at
// flat (4*wid+k)*256 + 4*ln, k=0..3 -> every store instruction is a fully
// wave-contiguous 1KB (16 complete 64B lines). No max-subtraction (logits
// sigma~1, max << 88, fp32 exp can't overflow); log2e folded into u[].
__device__ __forceinline__ void scores_body(const float* __restrict__ vp,
                                            const float* __restrict__ qp,
                                            const float* __restrict__ ap,
                                            float* __restrict__ out, int b,
                                            int t, float* SH) {
  const int s = b >> 4;
  const int i0 = (b & 15) * 4;
  float* tqL = SH;
  float* taL = SH + 512;
  float* uL = SH + 1024;                       // [ii][c]
  float(*redS)[4] = (float(*)[4])(SH + 1056);  // [ii][wid]
  if (t < 128)
    ((float4*)tqL)[t] = ((const float4*)(qp + s * 512))[t];
  else
    ((float4*)taL)[t - 128] = ((const float4*)(ap + s * 512))[t - 128];
  if (t < 32) {
    int ii = t >> 3, c = t & 7;
    uL[t] = vp[s * 512 + c * 64 + i0 + ii] * (INV_SCALE * LOG2E);
  }
  __syncthreads();
  const int wid = t >> 6, ln = t & 63;
  const int jb = 16 * wid + (ln >> 4);  // j for k=0 (then +4 per k)
  const int lq = (ln & 15) * 4;         // l base (4 consecutive l)
  float acc[4][16];                     // [ii][k*4+e]
#pragma unroll
  for (int ii = 0; ii < 4; ++ii)
#pragma unroll
    for (int x = 0; x < 16; ++x) acc[ii][x] = 0.f;
#pragma unroll
  for (int c = 0; c < 8; ++c) {
    const float* tq_c = &tqL[c * 64 + jb];
    float tj0 = tq_c[0];
    float tj1 = tq_c[4];
    float tj2 = tq_c[8];
    float tj3 = tq_c[12];
    float4 ta4 = *reinterpret_cast<const float4*>(&taL[c * 64 + lq]);
#pragma unroll
    for (int ii = 0; ii < 4; ++ii) {
      float uv = uL[ii * 8 + c];
      float m0 = uv * tj0;
      float m1 = uv * tj1;
      float m2 = uv * tj2;
      float m3 = uv * tj3;
      acc[ii][0] = fmaf(m0, ta4.x, acc[ii][0]);
      acc[ii][1] = fmaf(m0, ta4.y, acc[ii][1]);
      acc[ii][2] = fmaf(m0, ta4.z, acc[ii][2]);
      acc[ii][3] = fmaf(m0, ta4.w, acc[ii][3]);
      acc[ii][4] = fmaf(m1, ta4.x, acc[ii][4]);
      acc[ii][5] = fmaf(m1, ta4.y, acc[ii][5]);
      acc[ii][6] = fmaf(m1, ta4.z, acc[ii][6]);
      acc[ii][7] = fmaf(m1, ta4.w, acc[ii][7]);
      acc[ii][8] = fmaf(m2, ta4.x, acc[ii][8]);
      acc[ii][9] = fmaf(m2, ta4.y, acc[ii][9]);
      acc[ii][10] = fmaf(m2, ta4.z, acc[ii][10]);
      acc[ii][11] = fmaf(m2, ta4.w, acc[ii][11]);
      acc[ii][12] = fmaf(m3, ta4.x, acc[ii][12]);
      acc[ii][13] = fmaf(m3, ta4.y, acc[ii][13]);
      acc[ii][14] = fmaf(m3, ta4.z, acc[ii][14]);
      acc[ii][15] = fmaf(m3, ta4.w, acc[ii][15]);
    }
  }
#pragma unroll
  for (int ii = 0; ii < 4; ++ii) {
    float sl = 0.f;
#pragma unroll
    for (int x = 0; x < 16; ++x) {
      float e = exp2f(acc[ii][x]);  // acc carries log2e scaling
      acc[ii][x] = e;
      sl += e;
    }
#pragma unroll
    for (int o = 32; o; o >>= 1) sl += __shfl_xor(sl, o);
    if (ln == 0) redS[ii][wid] = sl;
  }
  __syncthreads();
  const long sbase = 262144L + (long)s * 262144 + (long)i0 * 4096;
#pragma unroll
  for (int ii = 0; ii < 4; ++ii) {
    float tot = (redS[ii][0] + redS[ii][1]) + (redS[ii][2] + redS[ii][3]);
    float sc = 1.0f / tot;
    // 4 stores, each wave-contiguous 1KB: float4 at base + k*256 + ln*4
    float* ob = out + sbase + ii * 4096 + wid * 1024 + ln * 4;
#pragma unroll
    for (int k = 0; k < 4; ++k) {
      *reinterpret_cast<float4*>(ob + k * 256) =
          make_float4(acc[ii][k * 4 + 0] * sc, acc[ii][k * 4 + 1] * sc,
                      acc[ii][k * 4 + 2] * sc, acc[ii][k * 4 + 3] * sc);
    }
  }
}

__global__ __launch_bounds__(256) void fused_kernel(FusedArgs F) {
  __shared__ float SH[6160];  // 4096 (WL) + 16*129 (XT) = 24.6 KB
  const int b = blockIdx.x;
  if (b < 256)
    proj2_direct_body(F, b, threadIdx.x, SH);
  else
    scores_body(F.vp, F.qp, F.ap, F.out, b - 256, threadIdx.x, SH);
}

extern "C" void kernel_launch(void* const* d_in, const int* in_sizes, int n_in,
                              void* d_out, int out_size, void* d_ws, size_t ws_size,
                              hipStream_t stream) {
  // setup_inputs order: v,q,a,k, 4 masks (unused), then Wv,bv,Wq,bq,Wa,ba,Wk,bk,
  //                     Wvo,bvo,Wqo,bqo,Wao,bao,Wko,bko
  int wb = 8;
  if (n_in >= 5 && in_sizes[4] == 262144) wb = 4;  // defensive: masks absent
  const float* W[8];
  const float* B[8];
  for (int i = 0; i < 8; ++i) {
    W[i] = (const float*)d_in[wb + 2 * i];
    B[i] = (const float*)d_in[wb + 2 * i + 1];
  }
  float* ws = (float*)d_ws;
  float* vp = ws;
  float* qp = ws + 65536;
  float* ap = ws + 131072;
  float* kp = ws + 196608;
  float* out = (float*)d_out;

  // Stage 1: input projections (vp = v@Wv^T+bv, etc.) — 512 blocks, 2/CU
  Proj4Args a1;
  for (int i = 0; i < 4; ++i) {
    a1.x[i] = (const float*)d_in[i];
    a1.w[i] = W[i];
    a1.b[i] = B[i];
  }
  a1.y[0] = vp; a1.y[1] = qp; a1.y[2] = ap; a1.y[3] = kp;
  hipLaunchKernelGGL(proj4_kernel, dim3(512), dim3(256), 0, stream, a1);

  // Fused: stage-2 projections w/ direct final outputs (256) + scores (2048)
  FusedArgs F;
  for (int i = 0; i < 4; ++i) {
    F.w2[i] = W[4 + i];
    F.b2[i] = B[4 + i];
  }
  F.vp = vp; F.qp = qp; F.ap = ap; F.kp = kp; F.out = out;
  hipLaunchKernelGGL(fused_kernel, dim3(2304), dim3(256), 0, stream, F);
}